// Round 1
// baseline (23798.122 us; speedup 1.0000x reference)
//
#include <hip/hip_runtime.h>
#include <hip/hip_bf16.h>

// DirectionalConvLayer: x (8,64,256,256) f32, W (64,64,3,3) OIHW f32, b (64) f32.
// Row conv has height 1 + vpad 1 => only W[:,:,1,:] contributes (width-3 1D conv).
// Forward scan f[i] = elu(instnorm(conv(f[i-1]))) + x[i], f[0]=x[0];
// backward g[p] = elu(instnorm(conv(g[p+1]))) + f[p], g[255]=f[255].
// Decomposition: one block per n (8 blocks x 1024 threads); everything row-local
// stays in LDS; f-rows stored in d_out (backward overwrites in place).

#define CC 64
#define HH 256
#define WW 256
#define SF_PITCH 264  // bf16 elements; 264*2=528 B, 16B-aligned rows

__global__ __launch_bounds__(1024, 1) void dirconv_kernel(
    const float* __restrict__ x,
    const float* __restrict__ Wt,
    const float* __restrict__ bias,
    float* out)
{
    const int n  = blockIdx.x;
    const int t  = threadIdx.x;
    const int o  = t & 63;   // output channel (lane id within wave)
    const int wg = t >> 6;   // wave id 0..15 -> w-chunk
    const int w0 = wg * 16;

    __shared__ __hip_bfloat16 sW[CC][3][CC];     // [i][kw][o]  24576 B
    __shared__ __hip_bfloat16 sF[CC][SF_PITCH];  // row buf, idx = w+1 (pads at 0, 257)  33792 B
    __shared__ float sRed[16][CC];               // 4096 B
    __shared__ float sMean[CC];
    __shared__ float sRstd[CC];
    __shared__ float sBias[CC];
    // total ~63.2 KB static LDS

    // Stage weights: W[o][i][1][kw] -> sW[i][kw][o]
    for (int idx = t; idx < CC * CC * 3; idx += 1024) {
        int o_ = idx & 63;
        int kw = (idx >> 6) % 3;
        int i_ = idx / 192;
        sW[i_][kw][o_] = __float2bfloat16(Wt[o_ * 576 + i_ * 9 + 3 + kw]);
    }
    if (t < CC) sBias[t] = bias[t];

    const size_t nbase = (size_t)n * CC * HH * WW;

    // f[0] = x[:, :, 0, :] -> sF and out row 0
    for (int idx = t; idx < CC * WW; idx += 1024) {
        int c = idx >> 8;
        int w = idx & 255;
        float v = x[nbase + (size_t)c * (HH * WW) + w];
        sF[c][w + 1] = __float2bfloat16(v);
        out[nbase + (size_t)c * (HH * WW) + w] = v;
    }
    if (t < CC) {
        sF[t][0]      = __float2bfloat16(0.f);
        sF[t][WW + 1] = __float2bfloat16(0.f);
    }
    __syncthreads();

    const size_t tbase = nbase + (size_t)o * (HH * WW) + w0;

    for (int phase = 0; phase < 2; phase++) {
        const float* src = (phase == 0) ? x : out;  // forward adds x[i]; backward adds f[p] (from out)
        const int row_start = (phase == 0) ? 1 : HH - 2;
        const int row_end   = (phase == 0) ? HH : -1;
        const int row_inc   = (phase == 0) ? 1 : -1;

        for (int row = row_start; row != row_end; row += row_inc) {
            // ---- conv: acc[k] = sum_i sum_kw W[o][i][kw] * fprev[i][w0+k+kw-1]
            float acc[16];
            #pragma unroll
            for (int k = 0; k < 16; k++) acc[k] = 0.f;

            for (int i = 0; i < CC; i++) {
                // 18 bf16 values sF[i][w0 .. w0+17]  (wave-uniform broadcast reads)
                float fv[18];
                const uint32_t* pp = (const uint32_t*)&sF[i][w0];
                #pragma unroll
                for (int j = 0; j < 9; j++) {
                    uint32_t u = pp[j];
                    union { uint32_t u; float f; } lo, hi;
                    lo.u = u << 16;           // low half  = element 2j
                    hi.u = u & 0xffff0000u;   // high half = element 2j+1
                    fv[2 * j]     = lo.f;
                    fv[2 * j + 1] = hi.f;
                }
                float wk0 = __bfloat162float(sW[i][0][o]);
                float wk1 = __bfloat162float(sW[i][1][o]);
                float wk2 = __bfloat162float(sW[i][2][o]);
                #pragma unroll
                for (int k = 0; k < 16; k++)
                    acc[k] = fmaf(wk0, fv[k], fmaf(wk1, fv[k + 1], fmaf(wk2, fv[k + 2], acc[k])));
            }

            const float vb = sBias[o];
            float s = 0.f, ss = 0.f;
            #pragma unroll
            for (int k = 0; k < 16; k++) {
                acc[k] += vb;
                s  += acc[k];
                ss += acc[k] * acc[k];
            }

            // ---- instance-norm stats over w (256) per channel o
            sRed[wg][o] = s;
            __syncthreads();
            if (t < CC) {
                float tot = 0.f;
                #pragma unroll
                for (int j = 0; j < 16; j++) tot += sRed[j][t];
                sMean[t] = tot * (1.f / 256.f);
            }
            __syncthreads();
            sRed[wg][o] = ss;
            __syncthreads();
            if (t < CC) {
                float tot = 0.f;
                #pragma unroll
                for (int j = 0; j < 16; j++) tot += sRed[j][t];
                float m   = sMean[t];
                float var = tot * (1.f / 256.f) - m * m;
                sRstd[t] = rsqrtf(var + 1e-5f);
            }
            __syncthreads();

            // ---- normalize + elu + add source row; write out + sF
            const float m = sMean[o];
            const float r = sRstd[o];
            const size_t rb = tbase + (size_t)row * WW;
            #pragma unroll
            for (int k = 0; k < 16; k++) {
                float y = (acc[k] - m) * r;
                y = (y > 0.f) ? y : (__expf(y) - 1.f);  // elu
                float f = y + src[rb + k];
                out[rb + k] = f;
                sF[o][w0 + 1 + k] = __float2bfloat16(f);
            }
            __syncthreads();
        }
    }
}

extern "C" void kernel_launch(void* const* d_in, const int* in_sizes, int n_in,
                              void* d_out, int out_size, void* d_ws, size_t ws_size,
                              hipStream_t stream) {
    const float* x  = (const float*)d_in[0];
    const float* Wt = (const float*)d_in[1];
    const float* b  = (const float*)d_in[2];
    float* out = (float*)d_out;
    dirconv_kernel<<<8, 1024, 0, stream>>>(x, Wt, b, out);
}

// Round 2
// 2835.838 us; speedup vs baseline: 8.3919x; 8.3919x over previous
//
#include <hip/hip_runtime.h>
#include <hip/hip_bf16.h>

// DirectionalConvLayer on MI355X — MFMA version.
// x (8,64,256,256) f32, W (64,64,3,3) OIHW f32, b (64) f32.
// Row conv (height-1 rows, vpad 1) => width-3 1D conv using W[:,:,1,:] only.
// f[i] = elu(instnorm(conv(f[i-1]))) + x[i]; then backward scan over f.
// Bias is omitted: InstanceNorm (no affine) exactly cancels a per-channel shift.
//
// One block per n (8 blocks, 512 threads = 8 waves). Per row:
//   conv as GEMM  C[o][w] = sum_{i,kw} W[o,i,kw] * fprev[i][w+kw-1]
//   via v_mfma_f32_16x16x32_bf16: M=64(o), N=256(w), K=192 as 3 shifted K=64.
//   A (weights) held in 96 VGPRs for the whole kernel; B read from transposed
//   LDS row buffer sFT[w][i] (pitch 72 => 4-bank row skew, 2-way = free).
//   Wave `wg` covers full M, n-tiles {wg*32, wg*32+16}.
// Stats: butterfly shfl_xor over the 16 lanes of each quad-row group, then
// 8-wave LDS reduce by threads t<64. 3 barriers/row.

#define CC 64
#define HH 256
#define WW 256
#define PITCH 72  // bf16 elems per sFT row (144 B)

typedef short bf16x8 __attribute__((ext_vector_type(8)));
typedef short bf16x4 __attribute__((ext_vector_type(4)));
typedef float f32x4  __attribute__((ext_vector_type(4)));

__global__ __launch_bounds__(512, 2) void dirconv_mfma(
    const float* __restrict__ x,
    const float* __restrict__ Wt,
    const float* __restrict__ bias,
    float* out)
{
    const int n    = blockIdx.x;
    const int t    = threadIdx.x;
    const int wave = t >> 6;
    const int lane = t & 63;
    const int quad = lane >> 4;
    const int l16  = lane & 15;
    const int w0   = wave * 32;

    __shared__ __hip_bfloat16 sFT[258 * PITCH];   // [w+1][i], 37152 B (pads at 0, 257)
    __shared__ float sRedS[8][CC];                // per-wave partial sums
    __shared__ float sRedQ[8][CC];                // per-wave partial sum-of-squares
    __shared__ float sMean[CC];
    __shared__ float sRstd[CC];

    // ---- stage conv weights (middle row taps) into LDS scratch (reuse sFT) ----
    __hip_bfloat16* sWs = sFT;  // [kw][i][o] = 3*64*64 bf16 = 24576 B
    for (int idx = t; idx < CC * CC * 9; idx += 512) {
        int o = idx / 576; int rem = idx - o * 576;
        int i = rem / 9;   int p   = rem - i * 9;
        if (p >= 3 && p < 6)
            sWs[((p - 3) * CC + i) * CC + o] = __float2bfloat16(Wt[idx]);
    }
    __syncthreads();

    // A frags in regs: wA[mt][kw][q], elem j = W[o = mt*16+l16][i = q*32+quad*8+j]
    bf16x8 wA[4][3][2];
    for (int mt = 0; mt < 4; mt++)
        for (int kw = 0; kw < 3; kw++)
            for (int q = 0; q < 2; q++) {
                bf16x8 v;
                int o = mt * 16 + l16;
                #pragma unroll
                for (int j = 0; j < 8; j++) {
                    int i = q * 32 + quad * 8 + j;
                    v[j] = ((short*)sWs)[(kw * CC + i) * CC + o];
                }
                wA[mt][kw][q] = v;
            }
    __syncthreads();

    // ---- init: f0 = x row 0 -> sFT (bf16) and out (f32); zero pads ----
    const size_t nbase = (size_t)n * CC * HH * WW;
    for (int idx = t; idx < CC * WW; idx += 512) {
        int c = idx >> 8, w = idx & 255;
        float v = x[nbase + (size_t)c * (HH * WW) + w];
        sFT[(w + 1) * PITCH + c] = __float2bfloat16(v);
        out[nbase + (size_t)c * (HH * WW) + w] = v;
    }
    if (t < CC) {
        sFT[0 * PITCH + t]   = __float2bfloat16(0.f);
        sFT[257 * PITCH + t] = __float2bfloat16(0.f);
    }
    __syncthreads();

    for (int phase = 0; phase < 2; phase++) {
        const float* src = (phase == 0) ? x : out;
        int row  = (phase == 0) ? 1 : HH - 2;
        int rend = (phase == 0) ? HH : -1;
        int rinc = (phase == 0) ? 1 : -1;

        for (; row != rend; row += rinc) {
            const size_t rowbase = nbase + (size_t)row * WW;

            // ---- prefetch src row (hidden behind conv phase) ----
            float srcv[2][4][4];
            #pragma unroll
            for (int nt = 0; nt < 2; nt++) {
                int w = w0 + nt * 16 + l16;
                #pragma unroll
                for (int mt = 0; mt < 4; mt++)
                    #pragma unroll
                    for (int r = 0; r < 4; r++) {
                        int o = mt * 16 + quad * 4 + r;
                        srcv[nt][mt][r] = src[rowbase + (size_t)o * (HH * WW) + w];
                    }
            }

            // ---- conv via MFMA ----
            f32x4 acc[2][4];
            #pragma unroll
            for (int nt = 0; nt < 2; nt++)
                #pragma unroll
                for (int mt = 0; mt < 4; mt++)
                    acc[nt][mt] = (f32x4){0.f, 0.f, 0.f, 0.f};

            #pragma unroll
            for (int nt = 0; nt < 2; nt++) {
                int wr = w0 + nt * 16 + l16;  // output w of this lane's B column
                #pragma unroll
                for (int kw = 0; kw < 3; kw++) {
                    // input w = wr + kw - 1; +1 pad shift => sFT row wr + kw
                    const __hip_bfloat16* rp = &sFT[(wr + kw) * PITCH];
                    #pragma unroll
                    for (int q = 0; q < 2; q++) {
                        bf16x8 bf = *(const bf16x8*)(rp + q * 32 + quad * 8);
                        #pragma unroll
                        for (int mt = 0; mt < 4; mt++)
                            acc[nt][mt] = __builtin_amdgcn_mfma_f32_16x16x32_bf16(
                                wA[mt][kw][q], bf, acc[nt][mt], 0, 0, 0);
                    }
                }
            }

            // ---- stats: s, ss per o (bias cancels under instance-norm) ----
            float sv[4][4], qv[4][4];
            #pragma unroll
            for (int mt = 0; mt < 4; mt++)
                #pragma unroll
                for (int r = 0; r < 4; r++) {
                    float a0 = acc[0][mt][r], a1 = acc[1][mt][r];
                    float s  = a0 + a1;
                    float ss = a0 * a0 + a1 * a1;
                    #pragma unroll
                    for (int m = 1; m < 16; m <<= 1) {
                        s  += __shfl_xor(s, m);
                        ss += __shfl_xor(ss, m);
                    }
                    sv[mt][r] = s; qv[mt][r] = ss;
                }
            if (l16 == 0) {
                #pragma unroll
                for (int mt = 0; mt < 4; mt++) {
                    *(f32x4*)&sRedS[wave][mt * 16 + quad * 4] =
                        (f32x4){sv[mt][0], sv[mt][1], sv[mt][2], sv[mt][3]};
                    *(f32x4*)&sRedQ[wave][mt * 16 + quad * 4] =
                        (f32x4){qv[mt][0], qv[mt][1], qv[mt][2], qv[mt][3]};
                }
            }
            __syncthreads();

            if (t < CC) {
                float s8 = 0.f, q8 = 0.f;
                #pragma unroll
                for (int j = 0; j < 8; j++) { s8 += sRedS[j][t]; q8 += sRedQ[j][t]; }
                float m   = s8 * (1.f / 256.f);
                float var = q8 * (1.f / 256.f) - m * m;
                sMean[t] = m;
                sRstd[t] = rsqrtf(var + 1e-5f);
            }
            __syncthreads();

            // ---- epilogue: normalize + elu + add src; write out + sFT ----
            #pragma unroll
            for (int mt = 0; mt < 4; mt++) {
                f32x4 mm = *(const f32x4*)&sMean[mt * 16 + quad * 4];
                f32x4 rr = *(const f32x4*)&sRstd[mt * 16 + quad * 4];
                #pragma unroll
                for (int nt = 0; nt < 2; nt++) {
                    int w = w0 + nt * 16 + l16;
                    bf16x4 pk;
                    #pragma unroll
                    for (int r = 0; r < 4; r++) {
                        float y = (acc[nt][mt][r] - mm[r]) * rr[r];
                        y = (y > 0.f) ? y : (__expf(y) - 1.f);
                        float f = y + srcv[nt][mt][r];
                        int o = mt * 16 + quad * 4 + r;
                        out[rowbase + (size_t)o * (HH * WW) + w] = f;
                        union { __hip_bfloat16 h; short s; } cv;
                        cv.h = __float2bfloat16(f);
                        pk[r] = cv.s;
                    }
                    // 4 consecutive o (reg dim) -> one 8 B LDS write
                    *(bf16x4*)&sFT[(w + 1) * PITCH + mt * 16 + quad * 4] = pk;
                }
            }
            __syncthreads();
        }
    }
}

extern "C" void kernel_launch(void* const* d_in, const int* in_sizes, int n_in,
                              void* d_out, int out_size, void* d_ws, size_t ws_size,
                              hipStream_t stream) {
    const float* x  = (const float*)d_in[0];
    const float* Wt = (const float*)d_in[1];
    const float* b  = (const float*)d_in[2];
    float* out = (float*)d_out;
    dirconv_mfma<<<8, 512, 0, stream>>>(x, Wt, b, out);
}

// Round 3
// 2162.282 us; speedup vs baseline: 11.0060x; 1.3115x over previous
//
#include <hip/hip_runtime.h>
#include <hip/hip_bf16.h>

// DirectionalConvLayer on MI355X — MFMA + DPP-stats version.
// x (8,64,256,256) f32, W (64,64,3,3) OIHW f32, b (64) f32.
// Height-1 rows with vpad 1 => width-3 1D conv using W[:,:,1,:] only.
// f[i] = elu(instnorm(conv(f[i-1]))) + x[i] forward; same backward over f.
// Bias omitted: InstanceNorm (no affine) exactly cancels per-channel shifts.
//
// One block per n (8 blocks, 512 threads = 8 waves). Conv as GEMM
// (M=64 o, N=256 w, K=192 (i,kw)) via v_mfma_f32_16x16x32_bf16; weights in
// 96 VGPRs/lane for the whole kernel; B from transposed LDS row buf sFT[w][i].
// Stats: per-(mt,r) DPP row_shr add-trees (VALU only, no LDS port) -> lane 15
// holds each 16-lane w-sum; cross-wave reduce split 8 channels/wave.
// Global out-stores issued after the last barrier (drain overlaps next conv).

#define CC 64
#define HH 256
#define WW 256
#define PITCH 72  // bf16 elems per sFT row (144 B, 16B-aligned)

typedef short bf16x8 __attribute__((ext_vector_type(8)));
typedef short bf16x4 __attribute__((ext_vector_type(4)));
typedef float f32x4  __attribute__((ext_vector_type(4)));

// Tree-sum within each 16-lane row via DPP row_shr; lane 15 of the row holds
// the full 16-lane sum on return (other lanes hold partials).
__device__ __forceinline__ float row16_sum_tail(float v) {
    float acc = v;
    int s;
    s = __builtin_amdgcn_update_dpp(0, __builtin_bit_cast(int, acc), 0x111, 0xF, 0xF, true);
    acc += __builtin_bit_cast(float, s);
    s = __builtin_amdgcn_update_dpp(0, __builtin_bit_cast(int, acc), 0x112, 0xF, 0xF, true);
    acc += __builtin_bit_cast(float, s);
    s = __builtin_amdgcn_update_dpp(0, __builtin_bit_cast(int, acc), 0x114, 0xF, 0xF, true);
    acc += __builtin_bit_cast(float, s);
    s = __builtin_amdgcn_update_dpp(0, __builtin_bit_cast(int, acc), 0x118, 0xF, 0xF, true);
    acc += __builtin_bit_cast(float, s);
    return acc;
}

__global__ __launch_bounds__(512, 2) void dirconv_mfma(
    const float* __restrict__ x,
    const float* __restrict__ Wt,
    const float* __restrict__ bias,
    float* out)
{
    const int n    = blockIdx.x;
    const int t    = threadIdx.x;
    const int wave = t >> 6;
    const int lane = t & 63;
    const int quad = lane >> 4;
    const int l16  = lane & 15;
    const int w0   = wave * 32;

    __shared__ __hip_bfloat16 sFT[258 * PITCH];   // [w+1][i], pads at 0 and 257
    __shared__ float sRedS[8][CC];
    __shared__ float sRedQ[8][CC];
    __shared__ float sMean[CC];
    __shared__ float sRstd[CC];

    // ---- stage conv weights (middle kernel row) via LDS scratch (reuse sFT) ----
    __hip_bfloat16* sWs = sFT;  // [kw][i][o]
    for (int idx = t; idx < CC * CC * 9; idx += 512) {
        int o = idx / 576; int rem = idx - o * 576;
        int i = rem / 9;   int p   = rem - i * 9;
        if (p >= 3 && p < 6)
            sWs[((p - 3) * CC + i) * CC + o] = __float2bfloat16(Wt[idx]);
    }
    __syncthreads();

    // A frags: wA[mt][kw][q], elem j = W[o = mt*16+l16][i = q*32+quad*8+j]
    bf16x8 wA[4][3][2];
    for (int mt = 0; mt < 4; mt++)
        for (int kw = 0; kw < 3; kw++)
            for (int q = 0; q < 2; q++) {
                bf16x8 v;
                int o = mt * 16 + l16;
                #pragma unroll
                for (int j = 0; j < 8; j++) {
                    int i = q * 32 + quad * 8 + j;
                    v[j] = ((short*)sWs)[(kw * CC + i) * CC + o];
                }
                wA[mt][kw][q] = v;
            }
    __syncthreads();

    // ---- init: f0 = x row 0 -> sFT (bf16) and out (f32); zero pads ----
    const size_t nbase = (size_t)n * CC * HH * WW;
    for (int idx = t; idx < CC * WW; idx += 512) {
        int c = idx >> 8, w = idx & 255;
        float v = x[nbase + (size_t)c * (HH * WW) + w];
        sFT[(w + 1) * PITCH + c] = __float2bfloat16(v);
        out[nbase + (size_t)c * (HH * WW) + w] = v;
    }
    if (t < CC) {
        sFT[0 * PITCH + t]   = __float2bfloat16(0.f);
        sFT[257 * PITCH + t] = __float2bfloat16(0.f);
    }
    __syncthreads();

    for (int phase = 0; phase < 2; phase++) {
        const float* src = (phase == 0) ? x : out;
        int row  = (phase == 0) ? 1 : HH - 2;
        int rend = (phase == 0) ? HH : -1;
        int rinc = (phase == 0) ? 1 : -1;

        for (; row != rend; row += rinc) {
            const size_t rowbase = nbase + (size_t)row * WW;

            // ---- prefetch src row (consumed in epilogue; hidden by conv) ----
            float srcv[2][4][4];
            #pragma unroll
            for (int nt = 0; nt < 2; nt++) {
                int w = w0 + nt * 16 + l16;
                #pragma unroll
                for (int mt = 0; mt < 4; mt++)
                    #pragma unroll
                    for (int r = 0; r < 4; r++) {
                        int o = mt * 16 + quad * 4 + r;
                        srcv[nt][mt][r] = src[rowbase + (size_t)o * (HH * WW) + w];
                    }
            }

            // ---- conv via MFMA ----
            f32x4 acc[2][4];
            #pragma unroll
            for (int nt = 0; nt < 2; nt++)
                #pragma unroll
                for (int mt = 0; mt < 4; mt++)
                    acc[nt][mt] = (f32x4){0.f, 0.f, 0.f, 0.f};

            #pragma unroll
            for (int nt = 0; nt < 2; nt++) {
                int wr = w0 + nt * 16 + l16;
                #pragma unroll
                for (int kw = 0; kw < 3; kw++) {
                    const __hip_bfloat16* rp = &sFT[(wr + kw) * PITCH];
                    #pragma unroll
                    for (int q = 0; q < 2; q++) {
                        bf16x8 bf = *(const bf16x8*)(rp + q * 32 + quad * 8);
                        #pragma unroll
                        for (int mt = 0; mt < 4; mt++)
                            acc[nt][mt] = __builtin_amdgcn_mfma_f32_16x16x32_bf16(
                                wA[mt][kw][q], bf, acc[nt][mt], 0, 0, 0);
                    }
                }
            }

            // ---- stats via DPP trees (no LDS port) ----
            float sv[4][4], qv[4][4];
            #pragma unroll
            for (int mt = 0; mt < 4; mt++)
                #pragma unroll
                for (int r = 0; r < 4; r++) {
                    float a0 = acc[0][mt][r], a1 = acc[1][mt][r];
                    sv[mt][r] = row16_sum_tail(a0 + a1);
                    qv[mt][r] = row16_sum_tail(fmaf(a0, a0, a1 * a1));
                }
            if (l16 == 15) {
                #pragma unroll
                for (int mt = 0; mt < 4; mt++) {
                    *(f32x4*)&sRedS[wave][mt * 16 + quad * 4] =
                        (f32x4){sv[mt][0], sv[mt][1], sv[mt][2], sv[mt][3]};
                    *(f32x4*)&sRedQ[wave][mt * 16 + quad * 4] =
                        (f32x4){qv[mt][0], qv[mt][1], qv[mt][2], qv[mt][3]};
                }
            }
            __syncthreads();

            // ---- cross-wave reduce: wave w handles channels [8w, 8w+8) ----
            if (lane < 8) {
                int o = wave * 8 + lane;
                float s8 = 0.f, q8 = 0.f;
                #pragma unroll
                for (int j = 0; j < 8; j++) { s8 += sRedS[j][o]; q8 += sRedQ[j][o]; }
                float m   = s8 * (1.f / 256.f);
                float var = q8 * (1.f / 256.f) - m * m;
                sMean[o] = m;
                sRstd[o] = rsqrtf(var + 1e-5f);
            }
            __syncthreads();

            // ---- epilogue: normalize + elu + add src; write sFT; defer out ----
            float fv[2][4][4];
            #pragma unroll
            for (int mt = 0; mt < 4; mt++) {
                f32x4 mm = *(const f32x4*)&sMean[mt * 16 + quad * 4];
                f32x4 rr = *(const f32x4*)&sRstd[mt * 16 + quad * 4];
                #pragma unroll
                for (int nt = 0; nt < 2; nt++) {
                    int w = w0 + nt * 16 + l16;
                    bf16x4 pk;
                    #pragma unroll
                    for (int r = 0; r < 4; r++) {
                        float y = (acc[nt][mt][r] - mm[r]) * rr[r];
                        y = (y > 0.f) ? y : (__expf(y) - 1.f);
                        float f = y + srcv[nt][mt][r];
                        fv[nt][mt][r] = f;
                        union { __hip_bfloat16 h; short s; } cv;
                        cv.h = __float2bfloat16(f);
                        pk[r] = cv.s;
                    }
                    *(bf16x4*)&sFT[(w + 1) * PITCH + mt * 16 + quad * 4] = pk;
                }
            }
            __syncthreads();

            // ---- global stores after the barrier: drain overlaps next conv ----
            #pragma unroll
            for (int nt = 0; nt < 2; nt++) {
                int w = w0 + nt * 16 + l16;
                #pragma unroll
                for (int mt = 0; mt < 4; mt++)
                    #pragma unroll
                    for (int r = 0; r < 4; r++) {
                        int o = mt * 16 + quad * 4 + r;
                        out[rowbase + (size_t)o * (HH * WW) + w] = fv[nt][mt][r];
                    }
            }
        }
    }
}

extern "C" void kernel_launch(void* const* d_in, const int* in_sizes, int n_in,
                              void* d_out, int out_size, void* d_ws, size_t ws_size,
                              hipStream_t stream) {
    const float* x  = (const float*)d_in[0];
    const float* Wt = (const float*)d_in[1];
    const float* b  = (const float*)d_in[2];
    float* out = (float*)d_out;
    dirconv_mfma<<<8, 512, 0, stream>>>(x, Wt, b, out);
}